// Round 3
// baseline (73.775 us; speedup 1.0000x reference)
//
#include <hip/hip_runtime.h>
#include <hip/hip_bf16.h>
#include <math.h>

#define DN     0.35355339059327373f   /* sqrt(1/8) */
#define RATIO  0.08838834764831845f   /* 1/sqrt(128) */
#define TEMP   0.125f
#define KLS    8.0f                   /* fixed key stabilizer: cancels exactly */

typedef short s16x8 __attribute__((ext_vector_type(8)));
typedef float f32x4 __attribute__((ext_vector_type(4)));

static __device__ __forceinline__ ushort f2bf(float f) {
    __hip_bfloat16 h = __float2bfloat16(f);
    return *reinterpret_cast<ushort*>(&h);
}
static __device__ __forceinline__ float bf2f(ushort u) {
    __hip_bfloat16 h = *reinterpret_cast<__hip_bfloat16*>(&u);
    return __bfloat162float(h);
}

// ---------------- feature kernel: blocks [0,512) = q, [512,1024) = k ----------
// Each block: stage proj once, process 16 rows (4 per wave).
__global__ __launch_bounds__(256) void feat_kernel(const float* __restrict__ qin,
    const float* __restrict__ kin, const float* __restrict__ proj,
    ushort* __restrict__ qp_b, ushort* __restrict__ qb, float* __restrict__ qls,
    ushort* __restrict__ kp_b, ushort* __restrict__ kb)
{
    __shared__ float pT[64 * 64];     // pT[e][r] = proj[r][e]
    int tid = threadIdx.x;
    bool isq = blockIdx.x < 512;
    const float* data = isq ? qin : kin;
    int bb = blockIdx.x & 511;
#pragma unroll
    for (int i = 0; i < 16; ++i) {
        int f = tid * 16 + i;
        pT[(f & 63) * 64 + (f >> 6)] = proj[f];
    }
    int wave = tid >> 6, lane = tid & 63;
    __syncthreads();

#pragma unroll
    for (int it = 0; it < 4; ++it) {
        int gid = bb * 16 + it * 4 + wave;          // gid = t*8 + h
        float x = data[((size_t)gid << 6) + lane];

        float qq = x * x;
#pragma unroll
        for (int m = 1; m < 64; m <<= 1) qq += __shfl_xor(qq, m, 64);
        float diag = 0.0625f * qq;

        float d0 = 0.f, d1 = 0.f, d2 = 0.f, d3 = 0.f;
#pragma unroll
        for (int e = 0; e < 64; e += 4) {
            d0 += __shfl(x, e,     64) * pT[(e    ) * 64 + lane];
            d1 += __shfl(x, e + 1, 64) * pT[(e + 1) * 64 + lane];
            d2 += __shfl(x, e + 2, 64) * pT[(e + 2) * 64 + lane];
            d3 += __shfl(x, e + 3, 64) * pT[(e + 3) * 64 + lane];
        }
        float dash = DN * ((d0 + d1) + (d2 + d3));

        if (isq) {
            float ad = fabsf(dash);
#pragma unroll
            for (int m = 1; m < 64; m <<= 1) ad = fmaxf(ad, __shfl_xor(ad, m, 64));
            qp_b[((size_t)gid << 7) + lane]      = f2bf(RATIO * __expf(dash - ad));
            qp_b[((size_t)gid << 7) + 64 + lane] = f2bf(RATIO * __expf(-dash - ad));
            qb[((size_t)gid << 6) + lane] = f2bf(x);
            if (lane == 0) qls[gid] = ad - diag;
        } else {
            float c = diag + KLS;
            kp_b[((size_t)gid << 7) + lane]      = f2bf(RATIO * __expf(dash - c));
            kp_b[((size_t)gid << 7) + 64 + lane] = f2bf(RATIO * __expf(-dash - c));
            kb[((size_t)gid << 6) + lane] = f2bf(x);
        }
    }
}

// ---------------- kv partials + v-transpose ----------------
// grid 256 = (h, 32-s-chunk). Also writes vT_b[h][d][s] bf16.
__global__ __launch_bounds__(256) void kv_kernel(const ushort* __restrict__ kp_b,
    const float* __restrict__ vin, ushort* __restrict__ vT_b,
    float* __restrict__ pkv, float* __restrict__ pksum)
{
    __shared__ float v_lds[32][68];
    int tid = threadIdx.x;
    int h = blockIdx.x >> 5, c = blockIdx.x & 31;
    int s0 = c * 32;
#pragma unroll
    for (int i = 0; i < 8; ++i) {
        int f = tid + 256 * i;                      // 2048 elems
        int sl = f >> 6, e = f & 63;
        v_lds[sl][e] = vin[((size_t)((s0 + sl) * 8 + h) << 6) + e];
    }
    __syncthreads();

    // vT_b[h*64+d][s0+sidx] = v[s0+sidx][d]
#pragma unroll
    for (int j = 0; j < 8; ++j) {
        int o = tid + 256 * j;                      // 2048
        int d = o >> 5, sidx = o & 31;
        vT_b[((size_t)(h * 64 + d) << 10) + s0 + sidx] = f2bf(v_lds[sidx][d]);
    }

    int m = tid & 127, sg = tid >> 7;
    int dbase = sg * 32;
    f32x4 acc[8];
#pragma unroll
    for (int i = 0; i < 8; ++i) acc[i] = (f32x4){0.f, 0.f, 0.f, 0.f};
    float ks = 0.f;
    for (int sl = 0; sl < 32; ++sl) {
        float kpv = bf2f(kp_b[((size_t)((s0 + sl) * 8 + h) << 7) + m]);
        ks += kpv;
        const f32x4* vp = (const f32x4*)&v_lds[sl][dbase];
#pragma unroll
        for (int i = 0; i < 8; ++i) {
            f32x4 v4 = vp[i];
            acc[i].x += kpv * v4.x; acc[i].y += kpv * v4.y;
            acc[i].z += kpv * v4.z; acc[i].w += kpv * v4.w;
        }
    }
    f32x4* dst = (f32x4*)(pkv + (((size_t)((h * 32 + c) * 128 + m)) << 6) + dbase);
#pragma unroll
    for (int i = 0; i < 8; ++i) dst[i] = acc[i];
    if (sg == 0) pksum[(h * 32 + c) * 128 + m] = ks;
}

// ---------------- reduce partials -> kvT_b (bf16), ksum (f32) ----------------
// grid 64 = (h, m-group of 16)
__global__ __launch_bounds__(256) void kvred_kernel(const float* __restrict__ pkv,
    const float* __restrict__ pksum, ushort* __restrict__ kvT_b, float* __restrict__ ksum)
{
    __shared__ float t_lds[16][68];
    int tid = threadIdx.x;
    int h = blockIdx.x >> 3, g = blockIdx.x & 7;
#pragma unroll
    for (int j = 0; j < 4; ++j) {
        int o = tid + 256 * j;                      // 1024 = 16m x 64d
        int mp = o >> 6, d = o & 63;
        int m = g * 16 + mp;
        float s = 0.f;
        for (int c = 0; c < 32; ++c)
            s += pkv[(((size_t)((h * 32 + c) * 128 + m)) << 6) + d];
        t_lds[mp][d] = s;
    }
    if (tid < 16) {
        float s = 0.f;
        for (int c = 0; c < 32; ++c) s += pksum[(h * 32 + c) * 128 + g * 16 + tid];
        ksum[h * 128 + g * 16 + tid] = s;
    }
    __syncthreads();
#pragma unroll
    for (int j = 0; j < 4; ++j) {
        int o = tid + 256 * j;
        int d = o >> 4, mp = o & 15;
        kvT_b[((size_t)(h * 64 + d) << 7) + g * 16 + mp] = f2bf(t_lds[mp][d]);
    }
}

// ---------------- main: MFMA local window + long-range combine ----------------
__global__ __launch_bounds__(512) void main_kernel(
    const ushort* __restrict__ qp_b, const ushort* __restrict__ qb,
    const float* __restrict__ qls, const ushort* __restrict__ kb,
    const ushort* __restrict__ kp_b, const ushort* __restrict__ vT_b,
    const ushort* __restrict__ kvT_b, const float* __restrict__ ksum,
    float* __restrict__ outp)
{
    __shared__ float QKb[32][168];
    __shared__ float DPb[32][168];
    __shared__ ushort ATb[32][168];
    __shared__ float qk1s[32], plss[32], lns[32], pss[32];

    int tid = threadIdx.x;
    int h = blockIdx.x >> 5, t0 = (blockIdx.x & 31) << 5;
    int lane = tid & 63, w = tid >> 6;
    int tl = tid >> 4, sub = tid & 15;
    int l15 = lane & 15, lk = lane >> 4;

    // ---- phase 0: row scalars ----
    {
        int gid = (t0 + tl) * 8 + h;
        const ushort* qpp = qp_b + ((size_t)gid << 7) + sub * 8;
        const float* ksp = ksum + h * 128 + sub * 8;
        float s = 0.f;
#pragma unroll
        for (int i = 0; i < 8; ++i) s += bf2f(qpp[i]) * ksp[i];
#pragma unroll
        for (int m = 1; m < 16; m <<= 1) s += __shfl_xor(s, m, 16);
        if (sub == 0) qk1s[tl] = s;
        if (sub == 1) plss[tl] = qls[gid] + KLS;
    }

    // ---- phase 1: QK & DP GEMMs (A,B frags from global bf16) ----
    s16x8 aq[2][2], ap[2][4];
#pragma unroll
    for (int mt = 0; mt < 2; ++mt) {
        int tg = (t0 + mt * 16 + l15) * 8 + h;
#pragma unroll
        for (int kt = 0; kt < 2; ++kt)
            aq[mt][kt] = *(const s16x8*)(qb + ((size_t)tg << 6) + kt * 32 + lk * 8);
#pragma unroll
        for (int kt = 0; kt < 4; ++kt)
            ap[mt][kt] = *(const s16x8*)(qp_b + ((size_t)tg << 7) + kt * 32 + lk * 8);
    }
    for (int nt = w; nt < 10; nt += 8) {
        int srow = min(max(t0 - 64 + nt * 16 + l15, 0), 1023);
        int sgid = srow * 8 + h;
        s16x8 bk[2], bp[4];
#pragma unroll
        for (int kt = 0; kt < 2; ++kt)
            bk[kt] = *(const s16x8*)(kb + ((size_t)sgid << 6) + kt * 32 + lk * 8);
#pragma unroll
        for (int kt = 0; kt < 4; ++kt)
            bp[kt] = *(const s16x8*)(kp_b + ((size_t)sgid << 7) + kt * 32 + lk * 8);
        f32x4 aqk[2] = {{0,0,0,0},{0,0,0,0}}, adp[2] = {{0,0,0,0},{0,0,0,0}};
#pragma unroll
        for (int mt = 0; mt < 2; ++mt) {
#pragma unroll
            for (int kt = 0; kt < 2; ++kt)
                aqk[mt] = __builtin_amdgcn_mfma_f32_16x16x32_bf16(aq[mt][kt], bk[kt], aqk[mt], 0, 0, 0);
#pragma unroll
            for (int kt = 0; kt < 4; ++kt)
                adp[mt] = __builtin_amdgcn_mfma_f32_16x16x32_bf16(ap[mt][kt], bp[kt], adp[mt], 0, 0, 0);
        }
#pragma unroll
        for (int mt = 0; mt < 2; ++mt)
#pragma unroll
            for (int r = 0; r < 4; ++r) {
                int row = mt * 16 + lk * 4 + r, cs = nt * 16 + l15;
                QKb[row][cs] = TEMP * aqk[mt][r];
                DPb[row][cs] = adp[mt][r];
            }
    }
    __syncthreads();

    // ---- phase 1.5: row stats -> log_norm, prime_scale ----
    int clo = max(tl, 64 - t0);
    int chi = min(tl + 128, 1088 - t0);
    float mx = -1e30f, dsum = 0.f;
#pragma unroll
    for (int kk = 0; kk < 10; ++kk) {
        int cs = sub + 16 * kk;
        if (cs >= clo && cs < chi) {
            mx = fmaxf(mx, QKb[tl][cs]);
            dsum += DPb[tl][cs];
        }
    }
#pragma unroll
    for (int m = 1; m < 16; m <<= 1) {
        mx = fmaxf(mx, __shfl_xor(mx, m, 16));
        dsum += __shfl_xor(dsum, m, 16);
    }
    float se = 0.f;
#pragma unroll
    for (int kk = 0; kk < 10; ++kk) {
        int cs = sub + 16 * kk;
        if (cs >= clo && cs < chi) se += __expf(QKb[tl][cs] - mx);
    }
#pragma unroll
    for (int m = 1; m < 16; m <<= 1) se += __shfl_xor(se, m, 16);
    if (sub == 0) {
        float lse = mx + __logf(se);
        float lr = __logf(fmaxf(qk1s[tl] - dsum, 1e-24f)) + plss[tl];
        float mab = fmaxf(lse, lr);
        float ln = mab + log1pf(__expf(fminf(lse, lr) - mab));
        lns[tl] = ln;
        pss[tl] = __expf(plss[tl] - ln);
    }
    __syncthreads();

    // ---- phase 2a: attn_local -> bf16 s-aligned buffer (zeros outside window) ----
    {
        float ln = lns[tl], ps = pss[tl];
#pragma unroll
        for (int kk = 0; kk < 10; ++kk) {
            int cs = sub + 16 * kk;
            float att = 0.f;
            if (cs >= clo && cs < chi)
                att = __expf(QKb[tl][cs] - ln) - DPb[tl][cs] * ps;
            ATb[tl][cs] = f2bf(att);
        }
    }
    __syncthreads();

    // ---- phase 2b: out = attn_sb @ V + ps * (q' @ kv) ----
    int Mt = w >> 2, Nt = w & 3;
    int dtile = Nt * 16 + l15;
    f32x4 acc1 = {0,0,0,0}, acc2 = {0,0,0,0};
    const ushort* vTrow = vT_b + ((size_t)(h * 64 + dtile) << 10);
#pragma unroll
    for (int kt = 0; kt < 5; ++kt) {
        s16x8 a = *(const s16x8*)&ATb[Mt * 16 + l15][kt * 32 + lk * 8];
        int sc = t0 - 64 + kt * 32 + lk * 8;
        sc = min(max(sc, 0), 1016);
        s16x8 b = *(const s16x8*)(vTrow + sc);
        acc1 = __builtin_amdgcn_mfma_f32_16x16x32_bf16(a, b, acc1, 0, 0, 0);
    }
    const ushort* kvTrow = kvT_b + ((size_t)(h * 64 + dtile) << 7);
#pragma unroll
    for (int kt = 0; kt < 4; ++kt) {
        s16x8 b = *(const s16x8*)(kvTrow + kt * 32 + lk * 8);
        acc2 = __builtin_amdgcn_mfma_f32_16x16x32_bf16(ap[Mt][kt], b, acc2, 0, 0, 0);
    }
#pragma unroll
    for (int r = 0; r < 4; ++r) {
        int row = Mt * 16 + lk * 4 + r;
        int t = t0 + row;
        float val = acc1[r] + pss[row] * acc2[r];
        outp[((size_t)(t * 8 + h) << 6) + dtile] = val;
    }
}

extern "C" void kernel_launch(void* const* d_in, const int* in_sizes, int n_in,
                              void* d_out, int out_size, void* d_ws, size_t ws_size,
                              hipStream_t stream) {
    const float* q    = (const float*)d_in[0];
    const float* kk   = (const float*)d_in[1];
    const float* vv   = (const float*)d_in[2];
    const float* proj = (const float*)d_in[3];
    float* out = (float*)d_out;
    float* ws  = (float*)d_ws;

    ushort* qp_b  = (ushort*)(ws);             // 8192*128 bf16 (524288 f32)
    ushort* qb    = (ushort*)(ws + 524288);    // 8192*64  bf16 (262144)
    ushort* kp_b  = (ushort*)(ws + 786432);    // 8192*128 bf16 (524288)
    ushort* kb    = (ushort*)(ws + 1310720);   // 8192*64  bf16 (262144)
    float*  qls   = ws + 1572864;              // 8192
    float*  ksum  = ws + 1581056;              // 1024
    ushort* vT_b  = (ushort*)(ws + 1582080);   // 8*64*1024 bf16 (262144)
    ushort* kvT_b = (ushort*)(ws + 1844224);   // 8*64*128 bf16 (32768)
    float*  pkv   = ws + 1876992;              // 8*32*128*64 f32 (2097152)
    float*  pksum = ws + 3974144;              // 8*32*128 (32768) -> ends 4006912

    feat_kernel<<<1024, 256, 0, stream>>>(q, kk, proj, qp_b, qb, qls, kp_b, kb);
    kv_kernel<<<256, 256, 0, stream>>>(kp_b, vv, vT_b, pkv, pksum);
    kvred_kernel<<<64, 256, 0, stream>>>(pkv, pksum, kvT_b, ksum);
    main_kernel<<<256, 512, 0, stream>>>(qp_b, qb, qls, kb, kp_b, vT_b, kvT_b,
                                         ksum, out);
}

// Round 4
// 53.256 us; speedup vs baseline: 1.3853x; 1.3853x over previous
//
#include <hip/hip_runtime.h>
#include <hip/hip_bf16.h>
#include <math.h>

#define DN     0.35355339059327373f   /* sqrt(1/8) */
#define RATIO  0.08838834764831845f   /* 1/sqrt(128) */
#define TEMP   0.125f
#define KLS    8.0f                   /* fixed key stabilizer: cancels exactly */

typedef short s16x8 __attribute__((ext_vector_type(8)));
typedef float f32x4 __attribute__((ext_vector_type(4)));

static __device__ __forceinline__ ushort f2bf(float f) {
    __hip_bfloat16 h = __float2bfloat16(f);
    return *reinterpret_cast<ushort*>(&h);
}
static __device__ __forceinline__ float bf2f(ushort u) {
    __hip_bfloat16 h = *reinterpret_cast<__hip_bfloat16*>(&u);
    return __bfloat162float(h);
}
static __device__ __forceinline__ void split1(float x, ushort& hi, ushort& lo) {
    hi = f2bf(x);
    lo = f2bf(x - bf2f(hi));
}
static __device__ __forceinline__ s16x8 pack8(const ushort* u) {
    union { s16x8 v; ushort u[8]; } P;
#pragma unroll
    for (int i = 0; i < 8; ++i) P.u[i] = u[i];
    return P.v;
}
// load 8 consecutive f32, split into hi/lo bf16 frags; also return sum of squares
static __device__ __forceinline__ float load8_split(const float* p, s16x8& ho, s16x8& lo) {
    f32x4 a = *(const f32x4*)p;
    f32x4 b = *(const f32x4*)(p + 4);
    float v[8] = {a.x, a.y, a.z, a.w, b.x, b.y, b.z, b.w};
    ushort hu[8], lu[8];
    float ss = 0.f;
#pragma unroll
    for (int i = 0; i < 8; ++i) {
        ss += v[i] * v[i];
        hu[i] = f2bf(v[i]);
        lu[i] = f2bf(v[i] - bf2f(hu[i]));
    }
    ho = pack8(hu); lo = pack8(lu);
    return ss;
}

#define MFMA(a, b, c) __builtin_amdgcn_mfma_f32_16x16x32_bf16(a, b, c, 0, 0, 0)

// ================= K kernel: k-features + vT + partial kv/ksum =================
// grid 256 = (h<<5)|chunk, 256 thr. chunk = 32 s-rows.
__global__ __launch_bounds__(256) void k_kernel(const float* __restrict__ kin,
    const float* __restrict__ vin, const float* __restrict__ proj,
    ushort* __restrict__ kh, ushort* __restrict__ kl,
    ushort* __restrict__ kph, ushort* __restrict__ kpl,
    ushort* __restrict__ vT, float* __restrict__ pkv, float* __restrict__ pksum)
{
    __shared__ float v_lds[32][65];
    __shared__ float kp_lds[32][133];
    __shared__ float diag_lds[32];
    int tid = threadIdx.x;
    int h = blockIdx.x >> 5, c = blockIdx.x & 31, s0 = c * 32;
    int w = tid >> 6, lane = tid & 63, l15 = lane & 15, lk = lane >> 4;

    // ---- phase A: v->LDS, kh/kl split-store, A-frags + diag, dash MFMA ----
#pragma unroll
    for (int i = 0; i < 8; ++i) {
        int f = tid + 256 * i;
        int sl = f >> 6, e = f & 63;
        v_lds[sl][e] = vin[((size_t)((s0 + sl) * 8 + h) << 6) + e];
    }
#pragma unroll
    for (int i = 0; i < 8; ++i) {
        int f = tid + 256 * i;
        int sl = f >> 6, e = f & 63;
        size_t goff = ((size_t)((s0 + sl) * 8 + h) << 6) + e;
        ushort hi, lo; split1(kin[goff], hi, lo);
        kh[goff] = hi; kl[goff] = lo;
    }
    s16x8 ah[2][2], al[2][2];
    float qq[2] = {0.f, 0.f};
#pragma unroll
    for (int mt = 0; mt < 2; ++mt)
#pragma unroll
        for (int kt = 0; kt < 2; ++kt)
            qq[mt] += load8_split(kin + ((size_t)((s0 + mt * 16 + l15) * 8 + h) << 6)
                                  + kt * 32 + lk * 8, ah[mt][kt], al[mt][kt]);
    if (w == 0) {
#pragma unroll
        for (int mt = 0; mt < 2; ++mt) {
            float s = qq[mt];
            s += __shfl_xor(s, 16, 64);
            s += __shfl_xor(s, 32, 64);
            if (lk == 0) diag_lds[mt * 16 + l15] = 0.0625f * s;
        }
    }
    f32x4 dacc[2] = {{0,0,0,0},{0,0,0,0}};
#pragma unroll
    for (int kt = 0; kt < 2; ++kt) {
        s16x8 bh, bl;
        load8_split(proj + ((w * 16 + l15) << 6) + kt * 32 + lk * 8, bh, bl);
#pragma unroll
        for (int mt = 0; mt < 2; ++mt) {
            dacc[mt] = MFMA(ah[mt][kt], bh, dacc[mt]);
            dacc[mt] = MFMA(ah[mt][kt], bl, dacc[mt]);
            dacc[mt] = MFMA(al[mt][kt], bh, dacc[mt]);
        }
    }
    __syncthreads();

    // ---- phase B: kp from dash, vT transpose-store ----
#pragma unroll
    for (int mt = 0; mt < 2; ++mt)
#pragma unroll
        for (int j = 0; j < 4; ++j) {
            int t = mt * 16 + lk * 4 + j;
            int r = w * 16 + l15;
            float dash = DN * dacc[mt][j];
            float cc = diag_lds[t] + KLS;
            kp_lds[t][r]      = RATIO * __expf( dash - cc);
            kp_lds[t][64 + r] = RATIO * __expf(-dash - cc);
        }
#pragma unroll
    for (int j = 0; j < 8; ++j) {
        int o = tid + 256 * j;
        int d = o >> 5, sidx = o & 31;
        vT[((size_t)(h * 64 + d) << 10) + s0 + sidx] = f2bf(v_lds[sidx][d]);
    }
    __syncthreads();

    // ---- phase C: kph/kpl store, pksum, kv MFMA -> pkv ----
#pragma unroll
    for (int i = 0; i < 16; ++i) {
        int o = tid + 256 * i;
        int sl = o >> 7, m = o & 127;
        size_t goff = ((size_t)((s0 + sl) * 8 + h) << 7) + m;
        ushort hi, lo; split1(kp_lds[sl][m], hi, lo);
        kph[goff] = hi; kpl[goff] = lo;
    }
    if (tid < 128) {
        float s = 0.f;
#pragma unroll
        for (int sl = 0; sl < 32; ++sl) s += kp_lds[sl][tid];
        pksum[(h * 32 + c) * 128 + tid] = s;
    }
    s16x8 bv;
    {
        ushort tmp[8];
#pragma unroll
        for (int i = 0; i < 8; ++i) tmp[i] = f2bf(v_lds[lk * 8 + i][w * 16 + l15]);
        bv = pack8(tmp);
    }
    float* pkvb = pkv + (((size_t)((h * 32 + c) * 128)) << 6);
#pragma unroll
    for (int mt = 0; mt < 8; ++mt) {
        ushort tmp[8];
#pragma unroll
        for (int i = 0; i < 8; ++i) tmp[i] = f2bf(kp_lds[lk * 8 + i][mt * 16 + l15]);
        s16x8 a = pack8(tmp);
        f32x4 acc = {0, 0, 0, 0};
        acc = MFMA(a, bv, acc);
#pragma unroll
        for (int j = 0; j < 4; ++j) {
            int m = mt * 16 + lk * 4 + j;
            pkvb[((size_t)m << 6) + w * 16 + l15] = acc[j];
        }
    }
}

// ================= kvred: reduce partials -> kvT bf16, ksum f32 =================
// grid 256 = (h<<5)|g, g = m-group of 4.
__global__ __launch_bounds__(256) void kvred_kernel(const float* __restrict__ pkv,
    const float* __restrict__ pksum, ushort* __restrict__ kvT, float* __restrict__ ksum)
{
    __shared__ float t_lds[4][65];
    int tid = threadIdx.x;
    int h = blockIdx.x >> 5, g = blockIdx.x & 31;
    int mp = tid >> 6, d = tid & 63;
    int m = g * 4 + mp;
    float s = 0.f;
#pragma unroll
    for (int c = 0; c < 32; ++c)
        s += pkv[(((size_t)((h * 32 + c) * 128 + m)) << 6) + d];
    t_lds[mp][d] = s;
    if (tid < 4) {
        float ks = 0.f;
#pragma unroll
        for (int c = 0; c < 32; ++c) ks += pksum[(h * 32 + c) * 128 + g * 4 + tid];
        ksum[h * 128 + g * 4 + tid] = ks;
    }
    __syncthreads();
    int d2 = tid >> 2, mp2 = tid & 3;
    kvT[((size_t)(h * 64 + d2) << 7) + g * 4 + mp2] = f2bf(t_lds[mp2][d2]);
}

// ================= main: q-features + local window + combine =================
__global__ __launch_bounds__(512) void main_kernel(const float* __restrict__ qin,
    const float* __restrict__ proj, const ushort* __restrict__ kh,
    const ushort* __restrict__ kl, const ushort* __restrict__ kph,
    const ushort* __restrict__ kpl, const ushort* __restrict__ vT,
    const ushort* __restrict__ kvT, const float* __restrict__ ksum,
    float* __restrict__ outp)
{
    __shared__ float qp_lds[32][133];
    __shared__ float QKb[32][170];
    __shared__ float DPb[32][170];
    __shared__ ushort ATb[32][168];
    __shared__ float diag_lds[32], ad_part[4][32], ad_lds[32];
    __shared__ float qk1s[32], plss[32], lns[32], pss[32];

    int tid = threadIdx.x;
    int h = blockIdx.x >> 5, t0 = (blockIdx.x & 31) << 5;
    int w = tid >> 6, lane = tid & 63, l15 = lane & 15, lk = lane >> 4;
    int tl = tid >> 4, sub = tid & 15;

    // ---- phase A: q A-frags (both mt) + diag + dash MFMA (unit mt_u,nt_u) ----
    s16x8 aqh[2][2], aql[2][2];
    float qq[2] = {0.f, 0.f};
#pragma unroll
    for (int mt = 0; mt < 2; ++mt)
#pragma unroll
        for (int kt = 0; kt < 2; ++kt)
            qq[mt] += load8_split(qin + ((size_t)((t0 + mt * 16 + l15) * 8 + h) << 6)
                                  + kt * 32 + lk * 8, aqh[mt][kt], aql[mt][kt]);
    if (w == 0) {
#pragma unroll
        for (int mt = 0; mt < 2; ++mt) {
            float s = qq[mt];
            s += __shfl_xor(s, 16, 64);
            s += __shfl_xor(s, 32, 64);
            if (lk == 0) diag_lds[mt * 16 + l15] = 0.0625f * s;
        }
    }
    int mt_u = w >> 2, nt_u = w & 3;
    f32x4 dacc = {0, 0, 0, 0};
#pragma unroll
    for (int kt = 0; kt < 2; ++kt) {
        s16x8 bh, bl;
        load8_split(proj + ((nt_u * 16 + l15) << 6) + kt * 32 + lk * 8, bh, bl);
        dacc = MFMA(aqh[mt_u][kt], bh, dacc);
        dacc = MFMA(aqh[mt_u][kt], bl, dacc);
        dacc = MFMA(aql[mt_u][kt], bh, dacc);
    }
    float rm[4];
#pragma unroll
    for (int j = 0; j < 4; ++j) {
        rm[j] = fabsf(DN * dacc[j]);
#pragma unroll
        for (int m = 1; m < 16; m <<= 1) rm[j] = fmaxf(rm[j], __shfl_xor(rm[j], m, 64));
    }
    if (l15 == 0) {
#pragma unroll
        for (int j = 0; j < 4; ++j) ad_part[nt_u][mt_u * 16 + lk * 4 + j] = rm[j];
    }
    __syncthreads();
    if (tid < 32) {
        float ad = fmaxf(fmaxf(ad_part[0][tid], ad_part[1][tid]),
                         fmaxf(ad_part[2][tid], ad_part[3][tid]));
        ad_lds[tid] = ad;
        plss[tid] = ad - diag_lds[tid] + KLS;
    }
    __syncthreads();
#pragma unroll
    for (int j = 0; j < 4; ++j) {
        int t = mt_u * 16 + lk * 4 + j;
        int r = nt_u * 16 + l15;
        float dash = DN * dacc[j];
        float ad = ad_lds[t];
        qp_lds[t][r]      = RATIO * __expf( dash - ad);
        qp_lds[t][64 + r] = RATIO * __expf(-dash - ad);
    }
    __syncthreads();

    // ---- phase D: qk1 + ap frags from qp_lds ----
    {
        const float* ksp = ksum + h * 128;
        float s = 0.f;
#pragma unroll
        for (int i = 0; i < 8; ++i) s += qp_lds[tl][sub * 8 + i] * ksp[sub * 8 + i];
#pragma unroll
        for (int m = 1; m < 16; m <<= 1) s += __shfl_xor(s, m, 16);
        if (sub == 0) qk1s[tl] = s;
    }
    s16x8 aph[2][4], apl[2][4];
#pragma unroll
    for (int mt = 0; mt < 2; ++mt)
#pragma unroll
        for (int kt = 0; kt < 4; ++kt) {
            ushort hu[8], lu[8];
#pragma unroll
            for (int i = 0; i < 8; ++i)
                split1(qp_lds[mt * 16 + l15][kt * 32 + lk * 8 + i], hu[i], lu[i]);
            aph[mt][kt] = pack8(hu); apl[mt][kt] = pack8(lu);
        }

    // ---- phase 1: QK & DP split-bf16 GEMMs ----
    for (int nt = w; nt < 10; nt += 8) {
        int srow = min(max(t0 - 64 + nt * 16 + l15, 0), 1023);
        size_t kbase = ((size_t)(srow * 8 + h)) << 6;
        size_t pbase = ((size_t)(srow * 8 + h)) << 7;
        s16x8 bkh[2], bkl[2], bph[4], bpl[4];
#pragma unroll
        for (int kt = 0; kt < 2; ++kt) {
            bkh[kt] = *(const s16x8*)(kh + kbase + kt * 32 + lk * 8);
            bkl[kt] = *(const s16x8*)(kl + kbase + kt * 32 + lk * 8);
        }
#pragma unroll
        for (int kt = 0; kt < 4; ++kt) {
            bph[kt] = *(const s16x8*)(kph + pbase + kt * 32 + lk * 8);
            bpl[kt] = *(const s16x8*)(kpl + pbase + kt * 32 + lk * 8);
        }
        f32x4 aqk[2] = {{0,0,0,0},{0,0,0,0}}, adp[2] = {{0,0,0,0},{0,0,0,0}};
#pragma unroll
        for (int mt = 0; mt < 2; ++mt) {
#pragma unroll
            for (int kt = 0; kt < 2; ++kt) {
                aqk[mt] = MFMA(aqh[mt][kt], bkh[kt], aqk[mt]);
                aqk[mt] = MFMA(aqh[mt][kt], bkl[kt], aqk[mt]);
                aqk[mt] = MFMA(aql[mt][kt], bkh[kt], aqk[mt]);
            }
#pragma unroll
            for (int kt = 0; kt < 4; ++kt) {
                adp[mt] = MFMA(aph[mt][kt], bph[kt], adp[mt]);
                adp[mt] = MFMA(aph[mt][kt], bpl[kt], adp[mt]);
                adp[mt] = MFMA(apl[mt][kt], bph[kt], adp[mt]);
            }
        }
#pragma unroll
        for (int mt = 0; mt < 2; ++mt)
#pragma unroll
            for (int r = 0; r < 4; ++r) {
                int row = mt * 16 + lk * 4 + r, cs = nt * 16 + l15;
                QKb[row][cs] = TEMP * aqk[mt][r];
                DPb[row][cs] = adp[mt][r];
            }
    }
    __syncthreads();

    // ---- phase 1.5: row stats -> log_norm, prime_scale ----
    int clo = max(tl, 64 - t0);
    int chi = min(tl + 128, 1088 - t0);
    float mx = -1e30f, dsum = 0.f;
#pragma unroll
    for (int kk = 0; kk < 10; ++kk) {
        int cs = sub + 16 * kk;
        if (cs >= clo && cs < chi) {
            mx = fmaxf(mx, QKb[tl][cs]);
            dsum += DPb[tl][cs];
        }
    }
#pragma unroll
    for (int m = 1; m < 16; m <<= 1) {
        mx = fmaxf(mx, __shfl_xor(mx, m, 16));
        dsum += __shfl_xor(dsum, m, 16);
    }
    float se = 0.f;
#pragma unroll
    for (int kk = 0; kk < 10; ++kk) {
        int cs = sub + 16 * kk;
        if (cs >= clo && cs < chi) se += __expf(QKb[tl][cs] - mx);
    }
#pragma unroll
    for (int m = 1; m < 16; m <<= 1) se += __shfl_xor(se, m, 16);
    if (sub == 0) {
        float lse = mx + __logf(se);
        float lr = __logf(fmaxf(qk1s[tl] - dsum, 1e-24f)) + plss[tl];
        float mab = fmaxf(lse, lr);
        float ln = mab + log1pf(__expf(fminf(lse, lr) - mab));
        lns[tl] = ln;
        pss[tl] = __expf(plss[tl] - ln);
    }
    __syncthreads();

    // ---- phase 2a: attn_local -> bf16 s-aligned buffer ----
    {
        float ln = lns[tl], ps = pss[tl];
#pragma unroll
        for (int kk = 0; kk < 10; ++kk) {
            int cs = sub + 16 * kk;
            float att = 0.f;
            if (cs >= clo && cs < chi)
                att = __expf(QKb[tl][cs] - ln) - DPb[tl][cs] * ps;
            ATb[tl][cs] = f2bf(att);
        }
    }
    __syncthreads();

    // ---- phase 2b: out = attn_sb @ V + ps * (q' @ kv) ----
    int Mt = w >> 2, Nt = w & 3;
    int dtile = Nt * 16 + l15;
    f32x4 acc1 = {0,0,0,0}, acc2 = {0,0,0,0};
    const ushort* vTrow = vT + ((size_t)(h * 64 + dtile) << 10);
#pragma unroll
    for (int kt = 0; kt < 5; ++kt) {
        s16x8 a = *(const s16x8*)&ATb[Mt * 16 + l15][kt * 32 + lk * 8];
        int sc = t0 - 64 + kt * 32 + lk * 8;
        sc = min(max(sc, 0), 1016);
        s16x8 b = *(const s16x8*)(vTrow + sc);
        acc1 = MFMA(a, b, acc1);
    }
    const ushort* kvTrow = kvT + ((size_t)(h * 64 + dtile) << 7);
#pragma unroll
    for (int kt = 0; kt < 4; ++kt) {
        s16x8 b = *(const s16x8*)(kvTrow + kt * 32 + lk * 8);
        acc2 = MFMA(aph[Mt][kt], b, acc2);
    }
#pragma unroll
    for (int r = 0; r < 4; ++r) {
        int row = Mt * 16 + lk * 4 + r;
        int t = t0 + row;
        float val = acc1[r] + pss[row] * acc2[r];
        outp[((size_t)(t * 8 + h) << 6) + dtile] = val;
    }
}

extern "C" void kernel_launch(void* const* d_in, const int* in_sizes, int n_in,
                              void* d_out, int out_size, void* d_ws, size_t ws_size,
                              hipStream_t stream) {
    const float* q    = (const float*)d_in[0];
    const float* kk   = (const float*)d_in[1];
    const float* vv   = (const float*)d_in[2];
    const float* proj = (const float*)d_in[3];
    float* out = (float*)d_out;
    float* ws  = (float*)d_ws;

    ushort* kh    = (ushort*)(ws);             // 8192*64 bf16 (262144 f32)
    ushort* kl    = (ushort*)(ws + 262144);    // 262144
    ushort* kph   = (ushort*)(ws + 524288);    // 8192*128 bf16 (524288)
    ushort* kpl   = (ushort*)(ws + 1048576);   // 524288
    ushort* vT    = (ushort*)(ws + 1572864);   // 8*64*1024 bf16 (262144)
    ushort* kvT   = (ushort*)(ws + 1835008);   // 8*64*128 bf16 (32768)
    float*  ksum  = ws + 1867776;              // 1024
    float*  pksum = ws + 1868800;              // 32768
    float*  pkv   = ws + 1901568;              // 8*32*128*64 (2097152) -> ends 3998720

    k_kernel<<<256, 256, 0, stream>>>(kk, vv, proj, kh, kl, kph, kpl, vT, pkv, pksum);
    kvred_kernel<<<256, 256, 0, stream>>>(pkv, pksum, kvT, ksum);
    main_kernel<<<256, 512, 0, stream>>>(q, proj, kh, kl, kph, kpl, vT, kvT, ksum, out);
}

// Round 5
// 48.405 us; speedup vs baseline: 1.5241x; 1.1002x over previous
//
#include <hip/hip_runtime.h>
#include <hip/hip_bf16.h>
#include <math.h>

#define DN     0.35355339059327373f   /* sqrt(1/8) */
#define RATIO  0.08838834764831845f   /* 1/sqrt(128) */
#define TEMP   0.125f
#define KLS    8.0f                   /* fixed key stabilizer: cancels exactly */

typedef short s16x8 __attribute__((ext_vector_type(8)));
typedef float f32x4 __attribute__((ext_vector_type(4)));

static __device__ __forceinline__ ushort f2bf(float f) {
    __hip_bfloat16 h = __float2bfloat16(f);
    return *reinterpret_cast<ushort*>(&h);
}
static __device__ __forceinline__ float bf2f(ushort u) {
    __hip_bfloat16 h = *reinterpret_cast<__hip_bfloat16*>(&u);
    return __bfloat162float(h);
}
static __device__ __forceinline__ void split1(float x, ushort& hi, ushort& lo) {
    hi = f2bf(x);
    lo = f2bf(x - bf2f(hi));
}
static __device__ __forceinline__ s16x8 pack8(const ushort* u) {
    union { s16x8 v; ushort u[8]; } P;
#pragma unroll
    for (int i = 0; i < 8; ++i) P.u[i] = u[i];
    return P.v;
}
static __device__ __forceinline__ float load8_split(const float* p, s16x8& ho, s16x8& lo) {
    f32x4 a = *(const f32x4*)p;
    f32x4 b = *(const f32x4*)(p + 4);
    float v[8] = {a.x, a.y, a.z, a.w, b.x, b.y, b.z, b.w};
    ushort hu[8], lu[8];
    float ss = 0.f;
#pragma unroll
    for (int i = 0; i < 8; ++i) {
        ss += v[i] * v[i];
        hu[i] = f2bf(v[i]);
        lu[i] = f2bf(v[i] - bf2f(hu[i]));
    }
    ho = pack8(hu); lo = pack8(lu);
    return ss;
}

#define MFMA(a, b, c) __builtin_amdgcn_mfma_f32_16x16x32_bf16(a, b, c, 0, 0, 0)

// ============ feat kernel: blocks [0,256) = k-side, [256,512) = q-side ============
// Each block: 32 rows of one head. k-side also produces vT + kv/ksum partials.
__global__ __launch_bounds__(256) void feat_kernel(const float* __restrict__ qin,
    const float* __restrict__ kin, const float* __restrict__ vin,
    const float* __restrict__ proj,
    ushort* __restrict__ qh, ushort* __restrict__ ql,
    ushort* __restrict__ qph, ushort* __restrict__ qpl, float* __restrict__ qls,
    ushort* __restrict__ kh, ushort* __restrict__ kl,
    ushort* __restrict__ kph, ushort* __restrict__ kpl,
    ushort* __restrict__ vT, ushort* __restrict__ pkv, float* __restrict__ pksum)
{
    __shared__ float v_lds[32][65];
    __shared__ float p_lds[32][133];
    __shared__ float diag_lds[32];
    __shared__ float ad_part[4][32];
    __shared__ float ad_lds[32];
    int tid = threadIdx.x;
    int isq = blockIdx.x >> 8;
    int bb = blockIdx.x & 255;
    int h = bb >> 5, c = bb & 31, s0 = c * 32;
    int w = tid >> 6, lane = tid & 63, l15 = lane & 15, lk = lane >> 4;
    const float* din = isq ? qin : kin;
    ushort* xh = isq ? qh : kh;
    ushort* xl = isq ? ql : kl;

    // split-store raw rows (bf16 hi/lo)
#pragma unroll
    for (int i = 0; i < 8; ++i) {
        int f = tid + 256 * i;
        int sl = f >> 6, e = f & 63;
        size_t goff = ((size_t)((s0 + sl) * 8 + h) << 6) + e;
        ushort hi, lo; split1(din[goff], hi, lo);
        xh[goff] = hi; xl[goff] = lo;
    }
    if (!isq) {
#pragma unroll
        for (int i = 0; i < 8; ++i) {
            int f = tid + 256 * i;
            int sl = f >> 6, e = f & 63;
            v_lds[sl][e] = vin[((size_t)((s0 + sl) * 8 + h) << 6) + e];
        }
    }

    // A-frags + row sum-of-squares
    s16x8 ah[2][2], al[2][2];
    float qq[2] = {0.f, 0.f};
#pragma unroll
    for (int mt = 0; mt < 2; ++mt)
#pragma unroll
        for (int kt = 0; kt < 2; ++kt)
            qq[mt] += load8_split(din + ((size_t)((s0 + mt * 16 + l15) * 8 + h) << 6)
                                  + kt * 32 + lk * 8, ah[mt][kt], al[mt][kt]);
    if (w == 0) {
#pragma unroll
        for (int mt = 0; mt < 2; ++mt) {
            float s = qq[mt];
            s += __shfl_xor(s, 16, 64);
            s += __shfl_xor(s, 32, 64);
            if (lk == 0) diag_lds[mt * 16 + l15] = 0.0625f * s;
        }
    }
    // dash via split-bf16 MFMA: rows (mt,lk,j), cols r = w*16+l15
    f32x4 dacc[2] = {{0,0,0,0},{0,0,0,0}};
#pragma unroll
    for (int kt = 0; kt < 2; ++kt) {
        s16x8 bh, bl;
        load8_split(proj + ((w * 16 + l15) << 6) + kt * 32 + lk * 8, bh, bl);
#pragma unroll
        for (int mt = 0; mt < 2; ++mt) {
            dacc[mt] = MFMA(ah[mt][kt], bh, dacc[mt]);
            dacc[mt] = MFMA(ah[mt][kt], bl, dacc[mt]);
            dacc[mt] = MFMA(al[mt][kt], bh, dacc[mt]);
        }
    }

    if (isq) {
        // per-row max |dash| over all 128 features (64 r, both signs)
#pragma unroll
        for (int mt = 0; mt < 2; ++mt)
#pragma unroll
            for (int j = 0; j < 4; ++j) {
                float rm = fabsf(DN * dacc[mt][j]);
#pragma unroll
                for (int m = 1; m < 16; m <<= 1) rm = fmaxf(rm, __shfl_xor(rm, m, 16));
                if (l15 == 0) ad_part[w][mt * 16 + lk * 4 + j] = rm;
            }
        __syncthreads();
        if (tid < 32) {
            float ad = fmaxf(fmaxf(ad_part[0][tid], ad_part[1][tid]),
                             fmaxf(ad_part[2][tid], ad_part[3][tid]));
            ad_lds[tid] = ad;
            qls[(size_t)((s0 + tid) * 8 + h)] = ad - diag_lds[tid];
        }
        __syncthreads();
#pragma unroll
        for (int mt = 0; mt < 2; ++mt)
#pragma unroll
            for (int j = 0; j < 4; ++j) {
                int t = mt * 16 + lk * 4 + j;
                int r = w * 16 + l15;
                float dash = DN * dacc[mt][j];
                float ad = ad_lds[t];
                p_lds[t][r]      = RATIO * __expf( dash - ad);
                p_lds[t][64 + r] = RATIO * __expf(-dash - ad);
            }
    } else {
        __syncthreads();   // diag_lds ready
#pragma unroll
        for (int mt = 0; mt < 2; ++mt)
#pragma unroll
            for (int j = 0; j < 4; ++j) {
                int t = mt * 16 + lk * 4 + j;
                int r = w * 16 + l15;
                float dash = DN * dacc[mt][j];
                float cc = diag_lds[t] + KLS;
                p_lds[t][r]      = RATIO * __expf( dash - cc);
                p_lds[t][64 + r] = RATIO * __expf(-dash - cc);
            }
        // vT[h*64+d][s0+sidx] = v[s0+sidx][d]
#pragma unroll
        for (int j = 0; j < 8; ++j) {
            int o = tid + 256 * j;
            int d = o >> 5, sidx = o & 31;
            vT[((size_t)(h * 64 + d) << 10) + s0 + sidx] = f2bf(v_lds[sidx][d]);
        }
    }
    __syncthreads();

    // split-store prime features
    ushort* ph = isq ? qph : kph;
    ushort* pl = isq ? qpl : kpl;
#pragma unroll
    for (int i = 0; i < 16; ++i) {
        int o = tid + 256 * i;
        int sl = o >> 7, m = o & 127;
        size_t goff = ((size_t)((s0 + sl) * 8 + h) << 7) + m;
        ushort hi, lo; split1(p_lds[sl][m], hi, lo);
        ph[goff] = hi; pl[goff] = lo;
    }
    if (!isq) {
        if (tid < 128) {
            float s = 0.f;
#pragma unroll
            for (int sl = 0; sl < 32; ++sl) s += p_lds[sl][tid];
            pksum[(h * 32 + c) * 128 + tid] = s;
        }
        s16x8 bv;
        {
            ushort tmp[8];
#pragma unroll
            for (int i = 0; i < 8; ++i) tmp[i] = f2bf(v_lds[lk * 8 + i][w * 16 + l15]);
            bv = pack8(tmp);
        }
        ushort* pkvb = pkv + (((size_t)((h * 32 + c) * 128)) << 6);
#pragma unroll
        for (int mt = 0; mt < 8; ++mt) {
            ushort tmp[8];
#pragma unroll
            for (int i = 0; i < 8; ++i) tmp[i] = f2bf(p_lds[lk * 8 + i][mt * 16 + l15]);
            s16x8 a = pack8(tmp);
            f32x4 acc = {0, 0, 0, 0};
            acc = MFMA(a, bv, acc);
#pragma unroll
            for (int j = 0; j < 4; ++j) {
                int m = mt * 16 + lk * 4 + j;
                pkvb[((size_t)m << 6) + w * 16 + l15] = f2bf(acc[j]);
            }
        }
    }
}

// ============ kvred: reduce partials -> kvT bf16, ksum f32 ============
__global__ __launch_bounds__(256) void kvred_kernel(const ushort* __restrict__ pkv,
    const float* __restrict__ pksum, ushort* __restrict__ kvT, float* __restrict__ ksum)
{
    __shared__ float t_lds[4][65];
    int tid = threadIdx.x;
    int h = blockIdx.x >> 5, g = blockIdx.x & 31;
    int mp = tid >> 6, d = tid & 63;
    int m = g * 4 + mp;
    float s = 0.f;
#pragma unroll
    for (int c = 0; c < 32; ++c)
        s += bf2f(pkv[(((size_t)((h * 32 + c) * 128 + m)) << 6) + d]);
    t_lds[mp][d] = s;
    if (tid < 4) {
        float ks = 0.f;
#pragma unroll
        for (int c = 0; c < 32; ++c) ks += pksum[(h * 32 + c) * 128 + g * 4 + tid];
        ksum[h * 128 + g * 4 + tid] = ks;
    }
    __syncthreads();
    int d2 = tid >> 2, mp2 = tid & 3;
    kvT[((size_t)(h * 64 + d2) << 7) + g * 4 + mp2] = f2bf(t_lds[mp2][d2]);
}

// ============ main: local window + long-range combine (pure GEMM + softmax) ======
__global__ __launch_bounds__(512) void main_kernel(
    const ushort* __restrict__ qh, const ushort* __restrict__ ql,
    const ushort* __restrict__ qph, const ushort* __restrict__ qpl,
    const float* __restrict__ qls,
    const ushort* __restrict__ kh, const ushort* __restrict__ kl,
    const ushort* __restrict__ kph, const ushort* __restrict__ kpl,
    const ushort* __restrict__ vT, const ushort* __restrict__ kvT,
    const float* __restrict__ ksum, float* __restrict__ outp)
{
    __shared__ float QKb[32][170];
    __shared__ float DPb[32][170];
    __shared__ ushort ATb[32][168];
    __shared__ float qk1s[32], plss[32], lns[32], pss[32];

    int tid = threadIdx.x;
    int h = blockIdx.x >> 5, t0 = (blockIdx.x & 31) << 5;
    int w = tid >> 6, lane = tid & 63, l15 = lane & 15, lk = lane >> 4;
    int tl = tid >> 4, sub = tid & 15;

    // ---- phase 0: row scalars qk1, pls ----
    {
        int gid = (t0 + tl) * 8 + h;
        const ushort* ph  = qph + ((size_t)gid << 7) + sub * 8;
        const ushort* plo = qpl + ((size_t)gid << 7) + sub * 8;
        const float* ksp = ksum + h * 128 + sub * 8;
        float s = 0.f;
#pragma unroll
        for (int i = 0; i < 8; ++i) s += (bf2f(ph[i]) + bf2f(plo[i])) * ksp[i];
#pragma unroll
        for (int m = 1; m < 16; m <<= 1) s += __shfl_xor(s, m, 16);
        if (sub == 0) qk1s[tl] = s;
        if (sub == 1) plss[tl] = qls[gid] + KLS;
    }

    // ---- A-fragments straight from global bf16 ----
    s16x8 aqh[2][2], aql[2][2], aph[2][4], apl[2][4];
#pragma unroll
    for (int mt = 0; mt < 2; ++mt) {
        int tg = (t0 + mt * 16 + l15) * 8 + h;
#pragma unroll
        for (int kt = 0; kt < 2; ++kt) {
            aqh[mt][kt] = *(const s16x8*)(qh + ((size_t)tg << 6) + kt * 32 + lk * 8);
            aql[mt][kt] = *(const s16x8*)(ql + ((size_t)tg << 6) + kt * 32 + lk * 8);
        }
#pragma unroll
        for (int kt = 0; kt < 4; ++kt) {
            aph[mt][kt] = *(const s16x8*)(qph + ((size_t)tg << 7) + kt * 32 + lk * 8);
            apl[mt][kt] = *(const s16x8*)(qpl + ((size_t)tg << 7) + kt * 32 + lk * 8);
        }
    }

    // ---- phase 1: QK & DP split-bf16 GEMMs ----
    for (int nt = w; nt < 10; nt += 8) {
        int srow = min(max(t0 - 64 + nt * 16 + l15, 0), 1023);
        size_t kbase = ((size_t)(srow * 8 + h)) << 6;
        size_t pbase = ((size_t)(srow * 8 + h)) << 7;
        s16x8 bkh[2], bkl[2], bph[4], bpl[4];
#pragma unroll
        for (int kt = 0; kt < 2; ++kt) {
            bkh[kt] = *(const s16x8*)(kh + kbase + kt * 32 + lk * 8);
            bkl[kt] = *(const s16x8*)(kl + kbase + kt * 32 + lk * 8);
        }
#pragma unroll
        for (int kt = 0; kt < 4; ++kt) {
            bph[kt] = *(const s16x8*)(kph + pbase + kt * 32 + lk * 8);
            bpl[kt] = *(const s16x8*)(kpl + pbase + kt * 32 + lk * 8);
        }
        f32x4 aqk[2] = {{0,0,0,0},{0,0,0,0}}, adp[2] = {{0,0,0,0},{0,0,0,0}};
#pragma unroll
        for (int mt = 0; mt < 2; ++mt) {
#pragma unroll
            for (int kt = 0; kt < 2; ++kt) {
                aqk[mt] = MFMA(aqh[mt][kt], bkh[kt], aqk[mt]);
                aqk[mt] = MFMA(aqh[mt][kt], bkl[kt], aqk[mt]);
                aqk[mt] = MFMA(aql[mt][kt], bkh[kt], aqk[mt]);
            }
#pragma unroll
            for (int kt = 0; kt < 4; ++kt) {
                adp[mt] = MFMA(aph[mt][kt], bph[kt], adp[mt]);
                adp[mt] = MFMA(aph[mt][kt], bpl[kt], adp[mt]);
                adp[mt] = MFMA(apl[mt][kt], bph[kt], adp[mt]);
            }
        }
#pragma unroll
        for (int mt = 0; mt < 2; ++mt)
#pragma unroll
            for (int r = 0; r < 4; ++r) {
                int row = mt * 16 + lk * 4 + r, cs = nt * 16 + l15;
                QKb[row][cs] = TEMP * aqk[mt][r];
                DPb[row][cs] = adp[mt][r];
            }
    }
    __syncthreads();

    // ---- phase 1.5: row stats -> log_norm, prime_scale ----
    int clo = max(tl, 64 - t0);
    int chi = min(tl + 128, 1088 - t0);
    float mx = -1e30f, dsum = 0.f;
#pragma unroll
    for (int kk = 0; kk < 10; ++kk) {
        int cs = sub + 16 * kk;
        if (cs >= clo && cs < chi) {
            mx = fmaxf(mx, QKb[tl][cs]);
            dsum += DPb[tl][cs];
        }
    }
#pragma unroll
    for (int m = 1; m < 16; m <<= 1) {
        mx = fmaxf(mx, __shfl_xor(mx, m, 16));
        dsum += __shfl_xor(dsum, m, 16);
    }
    float se = 0.f;
#pragma unroll
    for (int kk = 0; kk < 10; ++kk) {
        int cs = sub + 16 * kk;
        if (cs >= clo && cs < chi) se += __expf(QKb[tl][cs] - mx);
    }
#pragma unroll
    for (int m = 1; m < 16; m <<= 1) se += __shfl_xor(se, m, 16);
    if (sub == 0) {
        float lse = mx + __logf(se);
        float lr = __logf(fmaxf(qk1s[tl] - dsum, 1e-24f)) + plss[tl];
        float mab = fmaxf(lse, lr);
        float ln = mab + log1pf(__expf(fminf(lse, lr) - mab));
        lns[tl] = ln;
        pss[tl] = __expf(plss[tl] - ln);
    }
    __syncthreads();

    // ---- phase 2a: attn_local -> bf16 s-aligned buffer ----
    {
        float ln = lns[tl], ps = pss[tl];
#pragma unroll
        for (int kk = 0; kk < 10; ++kk) {
            int cs = sub + 16 * kk;
            float att = 0.f;
            if (cs >= clo && cs < chi)
                att = __expf(QKb[tl][cs] - ln) - DPb[tl][cs] * ps;
            ATb[tl][cs] = f2bf(att);
        }
    }
    __syncthreads();

    // ---- phase 2b: out = attn_sb @ V + ps * (q' @ kv) ----
    int Mt = w >> 2, Nt = w & 3;
    int dtile = Nt * 16 + l15;
    f32x4 acc1 = {0,0,0,0}, acc2 = {0,0,0,0};
    const ushort* vTrow = vT + ((size_t)(h * 64 + dtile) << 10);
#pragma unroll
    for (int kt = 0; kt < 5; ++kt) {
        s16x8 a = *(const s16x8*)&ATb[Mt * 16 + l15][kt * 32 + lk * 8];
        int sc = t0 - 64 + kt * 32 + lk * 8;
        sc = min(max(sc, 0), 1016);
        s16x8 b = *(const s16x8*)(vTrow + sc);
        acc1 = MFMA(a, b, acc1);
    }
    const ushort* kvTrow = kvT + ((size_t)(h * 64 + dtile) << 7);
#pragma unroll
    for (int kt = 0; kt < 4; ++kt) {
        s16x8 b = *(const s16x8*)(kvTrow + kt * 32 + lk * 8);
        acc2 = MFMA(aph[Mt][kt], b, acc2);
    }
#pragma unroll
    for (int r = 0; r < 4; ++r) {
        int row = Mt * 16 + lk * 4 + r;
        int t = t0 + row;
        float val = acc1[r] + pss[row] * acc2[r];
        outp[((size_t)(t * 8 + h) << 6) + dtile] = val;
    }
}

extern "C" void kernel_launch(void* const* d_in, const int* in_sizes, int n_in,
                              void* d_out, int out_size, void* d_ws, size_t ws_size,
                              hipStream_t stream) {
    const float* q    = (const float*)d_in[0];
    const float* kk   = (const float*)d_in[1];
    const float* vv   = (const float*)d_in[2];
    const float* proj = (const float*)d_in[3];
    float* out = (float*)d_out;
    float* ws  = (float*)d_ws;

    ushort* qh    = (ushort*)(ws);             // 8192*64 bf16 (262144 f32 slots)
    ushort* ql    = (ushort*)(ws + 262144);
    ushort* qph   = (ushort*)(ws + 524288);    // 8192*128 bf16 (524288)
    ushort* qpl   = (ushort*)(ws + 1048576);
    float*  qls   = ws + 1572864;              // 8192
    ushort* kh    = (ushort*)(ws + 1581056);   // 262144
    ushort* kl    = (ushort*)(ws + 1843200);
    ushort* kph   = (ushort*)(ws + 2105344);   // 524288
    ushort* kpl   = (ushort*)(ws + 2629632);
    ushort* vT    = (ushort*)(ws + 3153920);   // 8*64*1024 bf16 (262144)
    ushort* kvT   = (ushort*)(ws + 3416064);   // 8*64*128 bf16 (32768)
    float*  ksum  = ws + 3448832;              // 1024
    float*  pksum = ws + 3449856;              // 32768
    ushort* pkv   = (ushort*)(ws + 3482624);   // 8*32*128*64 bf16 (1048576) -> ends 4531200

    feat_kernel<<<512, 256, 0, stream>>>(q, kk, vv, proj, qh, ql, qph, qpl, qls,
                                         kh, kl, kph, kpl, vT, pkv, pksum);
    kvred_kernel<<<256, 256, 0, stream>>>(pkv, pksum, kvT, ksum);
    main_kernel<<<256, 512, 0, stream>>>(qh, ql, qph, qpl, qls, kh, kl, kph, kpl,
                                         vT, kvT, ksum, out);
}

// Round 6
// 31.564 us; speedup vs baseline: 2.3373x; 1.5335x over previous
//
#include <hip/hip_runtime.h>
#include <hip/hip_bf16.h>
#include <math.h>

#define DN     0.35355339059327373f   /* sqrt(1/8) */
#define RATIO  0.08838834764831845f   /* 1/sqrt(128) */
#define TEMP   0.125f
#define KLS    8.0f                   /* fixed key stabilizer: cancels exactly */

typedef short s16x8 __attribute__((ext_vector_type(8)));
typedef float f32x4 __attribute__((ext_vector_type(4)));

static __device__ __forceinline__ ushort f2bf(float f) {
    __hip_bfloat16 h = __float2bfloat16(f);
    return *reinterpret_cast<ushort*>(&h);
}
static __device__ __forceinline__ float bf2f(ushort u) {
    __hip_bfloat16 h = *reinterpret_cast<__hip_bfloat16*>(&u);
    return __bfloat162float(h);
}
static __device__ __forceinline__ void split1(float x, ushort& hi, ushort& lo) {
    hi = f2bf(x);
    lo = f2bf(x - bf2f(hi));
}
static __device__ __forceinline__ s16x8 pack8(const ushort* u) {
    union { s16x8 v; ushort u[8]; } P;
#pragma unroll
    for (int i = 0; i < 8; ++i) P.u[i] = u[i];
    return P.v;
}
static __device__ __forceinline__ float load8_split(const float* p, s16x8& ho, s16x8& lo) {
    f32x4 a = *(const f32x4*)p;
    f32x4 b = *(const f32x4*)(p + 4);
    float v[8] = {a.x, a.y, a.z, a.w, b.x, b.y, b.z, b.w};
    ushort hu[8], lu[8];
    float ss = 0.f;
#pragma unroll
    for (int i = 0; i < 8; ++i) {
        ss += v[i] * v[i];
        hu[i] = f2bf(v[i]);
        lu[i] = f2bf(v[i] - bf2f(hu[i]));
    }
    ho = pack8(hu); lo = pack8(lu);
    return ss;
}

#define MFMA(a, b, c) __builtin_amdgcn_mfma_f32_16x16x32_bf16(a, b, c, 0, 0, 0)

// ============ feat kernel: 512 blocks, h = blockIdx&7 (XCD-aligned) ============
// rest = blockIdx>>3: [0,32) = k-side chunks, [32,64) = q-side chunks (32 rows each)
__global__ __launch_bounds__(256) void feat_kernel(const float* __restrict__ qin,
    const float* __restrict__ kin, const float* __restrict__ vin,
    const float* __restrict__ proj,
    ushort* __restrict__ qh, ushort* __restrict__ ql,
    ushort* __restrict__ qph, ushort* __restrict__ qpl, float* __restrict__ qls,
    ushort* __restrict__ kh, ushort* __restrict__ kl,
    ushort* __restrict__ kph, ushort* __restrict__ kpl,
    ushort* __restrict__ vT, float* __restrict__ pkv, float* __restrict__ pksum)
{
    __shared__ float v_lds[32][65];
    __shared__ float p_lds[32][133];
    __shared__ float diag_lds[32];
    __shared__ float ad_part[4][32];
    __shared__ float ad_lds[32];
    int tid = threadIdx.x;
    int bid = blockIdx.x;
    int h = bid & 7, rest = bid >> 3;
    int isq = rest >> 5;
    int c = rest & 31, s0 = c * 32;
    int w = tid >> 6, lane = tid & 63, l15 = lane & 15, lk = lane >> 4;
    const float* din = isq ? qin : kin;
    ushort* xh = isq ? qh : kh;
    ushort* xl = isq ? ql : kl;

    // split-store raw rows (bf16 hi/lo)
#pragma unroll
    for (int i = 0; i < 8; ++i) {
        int f = tid + 256 * i;
        int sl = f >> 6, e = f & 63;
        size_t goff = ((size_t)((s0 + sl) * 8 + h) << 6) + e;
        ushort hi, lo; split1(din[goff], hi, lo);
        xh[goff] = hi; xl[goff] = lo;
    }
    if (!isq) {
#pragma unroll
        for (int i = 0; i < 8; ++i) {
            int f = tid + 256 * i;
            int sl = f >> 6, e = f & 63;
            v_lds[sl][e] = vin[((size_t)((s0 + sl) * 8 + h) << 6) + e];
        }
    }

    // A-frags + row sum-of-squares
    s16x8 ah[2][2], al[2][2];
    float qq[2] = {0.f, 0.f};
#pragma unroll
    for (int mt = 0; mt < 2; ++mt)
#pragma unroll
        for (int kt = 0; kt < 2; ++kt)
            qq[mt] += load8_split(din + ((size_t)((s0 + mt * 16 + l15) * 8 + h) << 6)
                                  + kt * 32 + lk * 8, ah[mt][kt], al[mt][kt]);
    if (w == 0) {
#pragma unroll
        for (int mt = 0; mt < 2; ++mt) {
            float s = qq[mt];
            s += __shfl_xor(s, 16, 64);
            s += __shfl_xor(s, 32, 64);
            if (lk == 0) diag_lds[mt * 16 + l15] = 0.0625f * s;
        }
    }
    // dash via split-bf16 MFMA
    f32x4 dacc[2] = {{0,0,0,0},{0,0,0,0}};
#pragma unroll
    for (int kt = 0; kt < 2; ++kt) {
        s16x8 bh, bl;
        load8_split(proj + ((w * 16 + l15) << 6) + kt * 32 + lk * 8, bh, bl);
#pragma unroll
        for (int mt = 0; mt < 2; ++mt) {
            dacc[mt] = MFMA(ah[mt][kt], bh, dacc[mt]);
            dacc[mt] = MFMA(ah[mt][kt], bl, dacc[mt]);
            dacc[mt] = MFMA(al[mt][kt], bh, dacc[mt]);
        }
    }

    if (isq) {
#pragma unroll
        for (int mt = 0; mt < 2; ++mt)
#pragma unroll
            for (int j = 0; j < 4; ++j) {
                float rm = fabsf(DN * dacc[mt][j]);
#pragma unroll
                for (int m = 1; m < 16; m <<= 1) rm = fmaxf(rm, __shfl_xor(rm, m, 16));
                if (l15 == 0) ad_part[w][mt * 16 + lk * 4 + j] = rm;
            }
        __syncthreads();
        if (tid < 32) {
            float ad = fmaxf(fmaxf(ad_part[0][tid], ad_part[1][tid]),
                             fmaxf(ad_part[2][tid], ad_part[3][tid]));
            ad_lds[tid] = ad;
            qls[(size_t)((s0 + tid) * 8 + h)] = ad - diag_lds[tid];
        }
        __syncthreads();
#pragma unroll
        for (int mt = 0; mt < 2; ++mt)
#pragma unroll
            for (int j = 0; j < 4; ++j) {
                int t = mt * 16 + lk * 4 + j;
                int r = w * 16 + l15;
                float dash = DN * dacc[mt][j];
                float ad = ad_lds[t];
                p_lds[t][r]      = RATIO * __expf( dash - ad);
                p_lds[t][64 + r] = RATIO * __expf(-dash - ad);
            }
    } else {
        __syncthreads();   // diag_lds ready
#pragma unroll
        for (int mt = 0; mt < 2; ++mt)
#pragma unroll
            for (int j = 0; j < 4; ++j) {
                int t = mt * 16 + lk * 4 + j;
                int r = w * 16 + l15;
                float dash = DN * dacc[mt][j];
                float cc = diag_lds[t] + KLS;
                p_lds[t][r]      = RATIO * __expf( dash - cc);
                p_lds[t][64 + r] = RATIO * __expf(-dash - cc);
            }
        // vT[h*64+d][s0+sidx] = v[s0+sidx][d]
#pragma unroll
        for (int j = 0; j < 8; ++j) {
            int o = tid + 256 * j;
            int d = o >> 5, sidx = o & 31;
            vT[((size_t)(h * 64 + d) << 10) + s0 + sidx] = f2bf(v_lds[sidx][d]);
        }
    }
    __syncthreads();

    // split-store prime features
    ushort* ph = isq ? qph : kph;
    ushort* pl = isq ? qpl : kpl;
#pragma unroll
    for (int i = 0; i < 16; ++i) {
        int o = tid + 256 * i;
        int sl = o >> 7, m = o & 127;
        size_t goff = ((size_t)((s0 + sl) * 8 + h) << 7) + m;
        ushort hi, lo; split1(p_lds[sl][m], hi, lo);
        ph[goff] = hi; pl[goff] = lo;
    }
    if (!isq) {
        if (tid < 128) {
            float s = 0.f;
#pragma unroll
            for (int sl = 0; sl < 32; ++sl) s += p_lds[sl][tid];
            pksum[(h * 32 + c) * 128 + tid] = s;
        }
        s16x8 bv;
        {
            ushort tmp[8];
#pragma unroll
            for (int i = 0; i < 8; ++i) tmp[i] = f2bf(v_lds[lk * 8 + i][w * 16 + l15]);
            bv = pack8(tmp);
        }
        float* pkvb = pkv + (((size_t)((h * 32 + c) * 128)) << 6);
#pragma unroll
        for (int mt = 0; mt < 8; ++mt) {
            ushort tmp[8];
#pragma unroll
            for (int i = 0; i < 8; ++i) tmp[i] = f2bf(p_lds[lk * 8 + i][mt * 16 + l15]);
            s16x8 a = pack8(tmp);
            f32x4 acc = {0, 0, 0, 0};
            acc = MFMA(a, bv, acc);
#pragma unroll
            for (int j = 0; j < 4; ++j) {
                int m = mt * 16 + lk * 4 + j;
                pkvb[((size_t)m << 6) + w * 16 + l15] = acc[j];
            }
        }
    }
}

// ============ kvred: 256 blocks, h = blockIdx&7; f32 partials -> kvT bf16 ========
__global__ __launch_bounds__(256) void kvred_kernel(const float* __restrict__ pkv,
    const float* __restrict__ pksum, ushort* __restrict__ kvT, float* __restrict__ ksum)
{
    __shared__ float t_lds[4][65];
    int tid = threadIdx.x;
    int h = blockIdx.x & 7, g = blockIdx.x >> 3;
    int mp = tid >> 6, d = tid & 63;
    int m = g * 4 + mp;
    float s = 0.f;
#pragma unroll
    for (int c = 0; c < 32; ++c)
        s += pkv[(((size_t)((h * 32 + c) * 128 + m)) << 6) + d];
    t_lds[mp][d] = s;
    if (tid < 4) {
        float ks = 0.f;
#pragma unroll
        for (int c = 0; c < 32; ++c) ks += pksum[(h * 32 + c) * 128 + g * 4 + tid];
        ksum[h * 128 + g * 4 + tid] = ks;
    }
    __syncthreads();
    int d2 = tid >> 2, mp2 = tid & 3;
    kvT[((size_t)(h * 64 + d2) << 7) + g * 4 + mp2] = f2bf(t_lds[mp2][d2]);
}

// ============ main: 512 blocks x 256 thr, 16-row tiles, h = blockIdx&7 ==========
__global__ __launch_bounds__(256) void main_kernel(
    const ushort* __restrict__ qh, const ushort* __restrict__ ql,
    const ushort* __restrict__ qph, const ushort* __restrict__ qpl,
    const float* __restrict__ qls,
    const ushort* __restrict__ kh, const ushort* __restrict__ kl,
    const ushort* __restrict__ kph, const ushort* __restrict__ kpl,
    const ushort* __restrict__ vT, const ushort* __restrict__ kvT,
    const float* __restrict__ ksum, float* __restrict__ outp)
{
    __shared__ float QKb[16][152];
    __shared__ float DPb[16][152];
    __shared__ ushort ATb[16][168];
    __shared__ float qk1s[16], plss[16], lns[16], pss[16];

    int tid = threadIdx.x;
    int h = blockIdx.x & 7, t0 = (blockIdx.x >> 3) << 4;
    int w = tid >> 6, lane = tid & 63, l15 = lane & 15, lk = lane >> 4;
    int tl = tid >> 4, sub = tid & 15;

    // ---- phase 0: prefetch kv B-frags (consumed at the very end) ----
    int dcol = w * 16 + l15;
    s16x8 bkv[4];
    {
        const ushort* kvTrow = kvT + ((size_t)(h * 64 + dcol) << 7);
#pragma unroll
        for (int kt = 0; kt < 4; ++kt)
            bkv[kt] = *(const s16x8*)(kvTrow + kt * 32 + lk * 8);
    }

    // ---- A-fragments (16 q-rows) ----
    s16x8 aqh[2], aql[2], aph[4], apl[4];
    {
        int tg = (t0 + l15) * 8 + h;
#pragma unroll
        for (int kt = 0; kt < 2; ++kt) {
            aqh[kt] = *(const s16x8*)(qh + ((size_t)tg << 6) + kt * 32 + lk * 8);
            aql[kt] = *(const s16x8*)(ql + ((size_t)tg << 6) + kt * 32 + lk * 8);
        }
#pragma unroll
        for (int kt = 0; kt < 4; ++kt) {
            aph[kt] = *(const s16x8*)(qph + ((size_t)tg << 7) + kt * 32 + lk * 8);
            apl[kt] = *(const s16x8*)(qpl + ((size_t)tg << 7) + kt * 32 + lk * 8);
        }
    }

    // ---- row scalars qk1, pls (16 rows x 16 threads) ----
    {
        int gid = (t0 + tl) * 8 + h;
        const ushort* ph  = qph + ((size_t)gid << 7) + sub * 8;
        const ushort* plo = qpl + ((size_t)gid << 7) + sub * 8;
        const float* ksp = ksum + h * 128 + sub * 8;
        float s = 0.f;
#pragma unroll
        for (int i = 0; i < 8; ++i) s += (bf2f(ph[i]) + bf2f(plo[i])) * ksp[i];
#pragma unroll
        for (int m = 1; m < 16; m <<= 1) s += __shfl_xor(s, m, 16);
        if (sub == 0) qk1s[tl] = s;
        if (sub == 1) plss[tl] = qls[gid] + KLS;
    }

    // ---- phase 1: QK & DP split-bf16 GEMMs over 9 window tiles ----
    for (int nt = w; nt < 9; nt += 4) {
        int srow = min(max(t0 - 64 + nt * 16 + l15, 0), 1023);
        size_t kbase = ((size_t)(srow * 8 + h)) << 6;
        size_t pbase = ((size_t)(srow * 8 + h)) << 7;
        s16x8 bkh[2], bkl[2], bph[4], bpl[4];
#pragma unroll
        for (int kt = 0; kt < 2; ++kt) {
            bkh[kt] = *(const s16x8*)(kh + kbase + kt * 32 + lk * 8);
            bkl[kt] = *(const s16x8*)(kl + kbase + kt * 32 + lk * 8);
        }
#pragma unroll
        for (int kt = 0; kt < 4; ++kt) {
            bph[kt] = *(const s16x8*)(kph + pbase + kt * 32 + lk * 8);
            bpl[kt] = *(const s16x8*)(kpl + pbase + kt * 32 + lk * 8);
        }
        f32x4 aqk = {0,0,0,0}, adp = {0,0,0,0};
#pragma unroll
        for (int kt = 0; kt < 2; ++kt) {
            aqk = MFMA(aqh[kt], bkh[kt], aqk);
            aqk = MFMA(aqh[kt], bkl[kt], aqk);
            aqk = MFMA(aql[kt], bkh[kt], aqk);
        }
#pragma unroll
        for (int kt = 0; kt < 4; ++kt) {
            adp = MFMA(aph[kt], bph[kt], adp);
            adp = MFMA(aph[kt], bpl[kt], adp);
            adp = MFMA(apl[kt], bph[kt], adp);
        }
#pragma unroll
        for (int r = 0; r < 4; ++r) {
            int row = lk * 4 + r, cs = nt * 16 + l15;
            QKb[row][cs] = TEMP * aqk[r];
            DPb[row][cs] = adp[r];
        }
    }
    __syncthreads();

    // ---- phase 1.5: row stats -> log_norm, prime_scale ----
    int clo = max(tl, 64 - t0);
    int chi = min(tl + 128, 1088 - t0);
    float mx = -1e30f, dsum = 0.f;
#pragma unroll
    for (int kk = 0; kk < 9; ++kk) {
        int cs = sub + 16 * kk;
        if (cs >= clo && cs < chi) {
            mx = fmaxf(mx, QKb[tl][cs]);
            dsum += DPb[tl][cs];
        }
    }
#pragma unroll
    for (int m = 1; m < 16; m <<= 1) {
        mx = fmaxf(mx, __shfl_xor(mx, m, 16));
        dsum += __shfl_xor(dsum, m, 16);
    }
    float se = 0.f;
#pragma unroll
    for (int kk = 0; kk < 9; ++kk) {
        int cs = sub + 16 * kk;
        if (cs >= clo && cs < chi) se += __expf(QKb[tl][cs] - mx);
    }
#pragma unroll
    for (int m = 1; m < 16; m <<= 1) se += __shfl_xor(se, m, 16);
    if (sub == 0) {
        float lse = mx + __logf(se);
        float lr = __logf(fmaxf(qk1s[tl] - dsum, 1e-24f)) + plss[tl];
        float mab = fmaxf(lse, lr);
        float ln = mab + log1pf(__expf(fminf(lse, lr) - mab));
        lns[tl] = ln;
        pss[tl] = __expf(plss[tl] - ln);
    }
    __syncthreads();

    // ---- phase 2a: attn_local -> bf16 s-aligned buffer (zeros outside window) ----
    {
        float ln = lns[tl], ps = pss[tl];
#pragma unroll
        for (int kk = 0; kk < 10; ++kk) {
            int cs = sub + 16 * kk;
            float att = 0.f;
            if (kk < 9 && cs >= clo && cs < chi)
                att = __expf(QKb[tl][cs] - ln) - DPb[tl][cs] * ps;
            ATb[tl][cs] = f2bf(att);
        }
    }
    __syncthreads();

    // ---- phase 2b: out = attn_sb @ V + ps * (q' @ kv) ----
    f32x4 acc1 = {0,0,0,0}, acc2 = {0,0,0,0};
    const ushort* vTrow = vT + ((size_t)(h * 64 + dcol) << 10);
#pragma unroll
    for (int kt = 0; kt < 5; ++kt) {
        s16x8 a = *(const s16x8*)&ATb[l15][kt * 32 + lk * 8];
        int sc = t0 - 64 + kt * 32 + lk * 8;
        sc = min(max(sc, 0), 1016);
        s16x8 b = *(const s16x8*)(vTrow + sc);
        acc1 = MFMA(a, b, acc1);
    }
#pragma unroll
    for (int kt = 0; kt < 4; ++kt)
        acc2 = MFMA(aph[kt], bkv[kt], acc2);
#pragma unroll
    for (int r = 0; r < 4; ++r) {
        int row = lk * 4 + r;
        float val = acc1[r] + pss[row] * acc2[r];
        outp[((size_t)((t0 + row) * 8 + h) << 6) + dcol] = val;
    }
}

extern "C" void kernel_launch(void* const* d_in, const int* in_sizes, int n_in,
                              void* d_out, int out_size, void* d_ws, size_t ws_size,
                              hipStream_t stream) {
    const float* q    = (const float*)d_in[0];
    const float* kk   = (const float*)d_in[1];
    const float* vv   = (const float*)d_in[2];
    const float* proj = (const float*)d_in[3];
    float* out = (float*)d_out;
    float* ws  = (float*)d_ws;

    ushort* qh    = (ushort*)(ws);             // 8192*64 bf16 (262144 f32 slots)
    ushort* ql    = (ushort*)(ws + 262144);
    ushort* qph   = (ushort*)(ws + 524288);    // 8192*128 bf16 (524288)
    ushort* qpl   = (ushort*)(ws + 1048576);
    float*  qls   = ws + 1572864;              // 8192
    ushort* kh    = (ushort*)(ws + 1581056);   // 262144
    ushort* kl    = (ushort*)(ws + 1843200);
    ushort* kph   = (ushort*)(ws + 2105344);   // 524288
    ushort* kpl   = (ushort*)(ws + 2629632);
    ushort* vT    = (ushort*)(ws + 3153920);   // 8*64*1024 bf16 (262144)
    ushort* kvT   = (ushort*)(ws + 3416064);   // 8*64*128 bf16 (32768)
    float*  ksum  = ws + 3448832;              // 1024
    float*  pksum = ws + 3449856;              // 32768
    float*  pkv   = ws + 3482624;              // 8*32*128*64 f32 (2097152) -> ends 5579776

    feat_kernel<<<512, 256, 0, stream>>>(q, kk, vv, proj, qh, ql, qph, qpl, qls,
                                         kh, kl, kph, kpl, vT, pkv, pksum);
    kvred_kernel<<<256, 256, 0, stream>>>(pkv, pksum, kvT, ksum);
    main_kernel<<<512, 256, 0, stream>>>(qh, ql, qph, qpl, qls, kh, kl, kph, kpl,
                                         vT, kvT, ksum, out);
}